// Round 1
// baseline (2224.328 us; speedup 1.0000x reference)
//
#include <hip/hip_runtime.h>

#define N_NODES 50000
#define N_EDGES 800000

// ---------------------------------------------------------------------------
// Edge scatter-add: agg[dst] += x[src], feature dim D (64 or 128).
// D/4 threads per edge, each handles one float4 chunk. Lanes covering one
// edge read 16B each from a contiguous 256B/512B row -> coalesced gather.
// Scatter is fp32 atomicAdd (device-scope by default on CDNA).
// ---------------------------------------------------------------------------
template <int D>
__global__ void scatter_add_kernel(const float* __restrict__ x,
                                   const int* __restrict__ src,
                                   const int* __restrict__ dst,
                                   float* __restrict__ agg,
                                   int n_edges) {
    constexpr int C = D / 4;  // float4 chunks per edge
    int t = blockIdx.x * blockDim.x + threadIdx.x;
    int e = t / C;
    int c = t % C;
    if (e >= n_edges) return;
    int s = src[e];
    int d = dst[e];
    const float4 v = *reinterpret_cast<const float4*>(x + (size_t)s * D + c * 4);
    float* p = agg + (size_t)d * D + c * 4;
    atomicAdd(p + 0, v.x);
    atomicAdd(p + 1, v.y);
    atomicAdd(p + 2, v.z);
    atomicAdd(p + 3, v.w);
}

// ---------------------------------------------------------------------------
// Fused GIN MLP: out = relu( relu((x+agg) @ Wa + ba) @ Wb + bb )
// Block = DH threads, processes ROWS rows. Input tile + hidden tile in LDS.
// Thread j owns hidden column j (phase 1) and output column j (phase 2, if
// j < DOUT). W reads coalesced across tid; LDS reads are wave-uniform
// broadcasts (free). ROWS=8 amortizes each W element over 8 FMAs.
// ---------------------------------------------------------------------------
template <int DIN, int DH, int DOUT, int ROWS>
__global__ __launch_bounds__(DH) void gin_mlp_kernel(
    const float* __restrict__ x, const float* __restrict__ agg,
    const float* __restrict__ Wa, const float* __restrict__ ba,
    const float* __restrict__ Wb, const float* __restrict__ bb,
    float* __restrict__ out, int n_rows) {
    __shared__ float t_lds[ROWS * DIN];
    __shared__ float hid_lds[ROWS * DH];

    const int row0 = blockIdx.x * ROWS;
    const int tid = threadIdx.x;

    // Stage (x + agg) for ROWS consecutive rows: contiguous, coalesced.
    constexpr int TOTAL = ROWS * DIN;
    for (int i = tid; i < TOTAL; i += DH) {
        int gr = row0 + i / DIN;
        float v = 0.0f;
        if (gr < n_rows) {
            size_t gi = (size_t)gr * DIN + (i % DIN);
            v = x[gi] + agg[gi];
        }
        t_lds[i] = v;
    }
    __syncthreads();

    // Hidden layer: hid[r][tid] = relu(ba[tid] + sum_k t[r][k] * Wa[k][tid])
    {
        float acc[ROWS];
        const float bias = ba[tid];
#pragma unroll
        for (int r = 0; r < ROWS; ++r) acc[r] = bias;
        for (int k = 0; k < DIN; ++k) {
            float w = Wa[k * DH + tid];
#pragma unroll
            for (int r = 0; r < ROWS; ++r) acc[r] = fmaf(t_lds[r * DIN + k], w, acc[r]);
        }
#pragma unroll
        for (int r = 0; r < ROWS; ++r) hid_lds[r * DH + tid] = fmaxf(acc[r], 0.0f);
    }
    __syncthreads();

    // Output layer: out[r][tid] = relu(bb[tid] + sum_k hid[r][k] * Wb[k][tid])
    if (tid < DOUT) {
        float acc[ROWS];
        const float bias = bb[tid];
#pragma unroll
        for (int r = 0; r < ROWS; ++r) acc[r] = bias;
        for (int k = 0; k < DH; ++k) {
            float w = Wb[k * DOUT + tid];
#pragma unroll
            for (int r = 0; r < ROWS; ++r) acc[r] = fmaf(hid_lds[r * DH + k], w, acc[r]);
        }
#pragma unroll
        for (int r = 0; r < ROWS; ++r) {
            int gr = row0 + r;
            if (gr < n_rows) out[(size_t)gr * DOUT + tid] = fmaxf(acc[r], 0.0f);
        }
    }
}

extern "C" void kernel_launch(void* const* d_in, const int* in_sizes, int n_in,
                              void* d_out, int out_size, void* d_ws, size_t ws_size,
                              hipStream_t stream) {
    const float* x   = (const float*)d_in[0];
    const int*   ei  = (const int*)d_in[1];   // [2, N_EDGES] int32
    const float* W1a = (const float*)d_in[2];
    const float* b1a = (const float*)d_in[3];
    const float* W1b = (const float*)d_in[4];
    const float* b1b = (const float*)d_in[5];
    const float* W2a = (const float*)d_in[6];
    const float* b2a = (const float*)d_in[7];
    const float* W2b = (const float*)d_in[8];
    const float* b2b = (const float*)d_in[9];
    float* out = (float*)d_out;

    const int* src = ei;
    const int* dst = ei + N_EDGES;

    // Workspace layout (fp32): agg1[N,64] | h[N,128] | agg2[N,128]
    float* agg1 = (float*)d_ws;
    float* h    = agg1 + (size_t)N_NODES * 64;
    float* agg2 = h + (size_t)N_NODES * 128;

    hipMemsetAsync(agg1, 0, (size_t)N_NODES * 64 * sizeof(float), stream);
    hipMemsetAsync(agg2, 0, (size_t)N_NODES * 128 * sizeof(float), stream);

    // Layer 1: agg1 = segment_sum(x[src], dst); h = mlp1(x + agg1)
    {
        int threads = N_EDGES * (64 / 4);
        scatter_add_kernel<64><<<(threads + 255) / 256, 256, 0, stream>>>(
            x, src, dst, agg1, N_EDGES);
        gin_mlp_kernel<64, 128, 128, 8><<<(N_NODES + 7) / 8, 128, 0, stream>>>(
            x, agg1, W1a, b1a, W1b, b1b, h, N_NODES);
    }

    // Layer 2: agg2 = segment_sum(h[src], dst); out = mlp2(h + agg2)
    {
        int threads = N_EDGES * (128 / 4);
        scatter_add_kernel<128><<<(threads + 255) / 256, 256, 0, stream>>>(
            h, src, dst, agg2, N_EDGES);
        gin_mlp_kernel<128, 128, 64, 8><<<(N_NODES + 7) / 8, 128, 0, stream>>>(
            h, agg2, W2a, b2a, W2b, b2b, out, N_NODES);
    }
}

// Round 2
// 476.528 us; speedup vs baseline: 4.6678x; 4.6678x over previous
//
#include <hip/hip_runtime.h>

#define N_NODES 50000
#define N_EDGES 800000

// ---------------------------------------------------------------------------
// CSR build (per launch; workspace is re-poisoned each call).
// deg[i] = #edges with dst==i  -> exclusive scan off[] -> fill nbr[] with src.
// Int atomics only (~1.6M total) — ~25us vs 2000us of float atomics.
// ---------------------------------------------------------------------------
__global__ void hist_kernel(const int* __restrict__ dst, int* __restrict__ deg,
                            int n) {
    int i = blockIdx.x * blockDim.x + threadIdx.x;
    if (i < n) atomicAdd(&deg[dst[i]], 1);
}

// Single-block exclusive scan over deg[0..n) -> off[0..n], cursor copy.
__global__ __launch_bounds__(1024) void scan_kernel(const int* __restrict__ deg,
                                                    int* __restrict__ off,
                                                    int* __restrict__ cursor,
                                                    int n) {
    __shared__ int sums[1024];
    const int tid = threadIdx.x;
    const int chunk = (n + 1023) / 1024;
    const int lo = tid * chunk;
    const int hi = min(lo + chunk, n);
    int s = 0;
    for (int i = lo; i < hi; ++i) s += deg[i];
    sums[tid] = s;
    __syncthreads();
    // Hillis-Steele inclusive scan over 1024 thread sums
    for (int d = 1; d < 1024; d <<= 1) {
        int v = (tid >= d) ? sums[tid - d] : 0;
        __syncthreads();
        sums[tid] += v;
        __syncthreads();
    }
    int run = sums[tid] - s;  // exclusive prefix of this thread's chunk
    for (int i = lo; i < hi; ++i) {
        off[i] = run;
        cursor[i] = run;
        run += deg[i];
    }
    if (tid == 1023) off[n] = run;  // == total edge count
}

__global__ void fill_kernel(const int* __restrict__ src,
                            const int* __restrict__ dst,
                            int* __restrict__ cursor, int* __restrict__ nbr,
                            int n) {
    int i = blockIdx.x * blockDim.x + threadIdx.x;
    if (i < n) {
        int pos = atomicAdd(&cursor[dst[i]], 1);
        nbr[pos] = src[i];
    }
}

// ---------------------------------------------------------------------------
// Gather aggregation: t[i] = x[i] + sum_{j in N(i)} x[j].  D/4 lanes per node,
// float4 per lane; each neighbor row read is a coalesced 256/512B burst from
// L2/LLC (x is 12.8/25.6 MB, cache-resident). No float atomics.
// ---------------------------------------------------------------------------
template <int D>
__global__ void gather_kernel(const float* __restrict__ x,
                              const int* __restrict__ off,
                              const int* __restrict__ nbr,
                              float* __restrict__ t, int n_nodes) {
    constexpr int C = D / 4;      // lanes per node
    constexpr int NPB = 256 / C;  // nodes per block
    const int tid = threadIdx.x;
    const int node = blockIdx.x * NPB + tid / C;
    const int c = tid % C;
    if (node >= n_nodes) return;
    const int lo = off[node];
    const int hi = off[node + 1];
    float4 acc = *reinterpret_cast<const float4*>(x + (size_t)node * D + c * 4);
    for (int j = lo; j < hi; ++j) {
        const int s = nbr[j];  // broadcast across the node's lane group
        const float4 v =
            *reinterpret_cast<const float4*>(x + (size_t)s * D + c * 4);
        acc.x += v.x; acc.y += v.y; acc.z += v.z; acc.w += v.w;
    }
    *reinterpret_cast<float4*>(t + (size_t)node * D + c * 4) = acc;
}

// ---------------------------------------------------------------------------
// Fused GIN MLP on pre-aggregated input t:
//   out = relu( relu(t @ Wa + ba) @ Wb + bb )
// Block = DH threads, ROWS rows per block. LDS reads are wave-uniform
// broadcasts; W reads coalesced across tid, amortized over ROWS FMAs.
// ---------------------------------------------------------------------------
template <int DIN, int DH, int DOUT, int ROWS>
__global__ __launch_bounds__(DH) void gin_mlp_kernel(
    const float* __restrict__ t, const float* __restrict__ Wa,
    const float* __restrict__ ba, const float* __restrict__ Wb,
    const float* __restrict__ bb, float* __restrict__ out, int n_rows) {
    __shared__ float t_lds[ROWS * DIN];
    __shared__ float hid_lds[ROWS * DH];

    const int row0 = blockIdx.x * ROWS;
    const int tid = threadIdx.x;

    constexpr int TOTAL = ROWS * DIN;
    for (int i = tid; i < TOTAL; i += DH) {
        int gr = row0 + i / DIN;
        t_lds[i] = (gr < n_rows) ? t[(size_t)gr * DIN + (i % DIN)] : 0.0f;
    }
    __syncthreads();

    {
        float acc[ROWS];
        const float bias = ba[tid];
#pragma unroll
        for (int r = 0; r < ROWS; ++r) acc[r] = bias;
        for (int k = 0; k < DIN; ++k) {
            float w = Wa[k * DH + tid];
#pragma unroll
            for (int r = 0; r < ROWS; ++r)
                acc[r] = fmaf(t_lds[r * DIN + k], w, acc[r]);
        }
#pragma unroll
        for (int r = 0; r < ROWS; ++r)
            hid_lds[r * DH + tid] = fmaxf(acc[r], 0.0f);
    }
    __syncthreads();

    if (tid < DOUT) {
        float acc[ROWS];
        const float bias = bb[tid];
#pragma unroll
        for (int r = 0; r < ROWS; ++r) acc[r] = bias;
        for (int k = 0; k < DH; ++k) {
            float w = Wb[k * DOUT + tid];
#pragma unroll
            for (int r = 0; r < ROWS; ++r)
                acc[r] = fmaf(hid_lds[r * DH + k], w, acc[r]);
        }
#pragma unroll
        for (int r = 0; r < ROWS; ++r) {
            int gr = row0 + r;
            if (gr < n_rows) out[(size_t)gr * DOUT + tid] = fmaxf(acc[r], 0.0f);
        }
    }
}

extern "C" void kernel_launch(void* const* d_in, const int* in_sizes, int n_in,
                              void* d_out, int out_size, void* d_ws,
                              size_t ws_size, hipStream_t stream) {
    const float* x   = (const float*)d_in[0];
    const int*   ei  = (const int*)d_in[1];  // [2, N_EDGES] int32
    const float* W1a = (const float*)d_in[2];
    const float* b1a = (const float*)d_in[3];
    const float* W1b = (const float*)d_in[4];
    const float* b1b = (const float*)d_in[5];
    const float* W2a = (const float*)d_in[6];
    const float* b2a = (const float*)d_in[7];
    const float* W2b = (const float*)d_in[8];
    const float* b2b = (const float*)d_in[9];
    float* out = (float*)d_out;

    const int* src = ei;
    const int* dst = ei + N_EDGES;

    // Workspace: t1[N,64] | h[N,128] | t2[N,128] | deg[N] off[N+1] cur[N] nbr[E]
    float* t1 = (float*)d_ws;
    float* h  = t1 + (size_t)N_NODES * 64;
    float* t2 = h + (size_t)N_NODES * 128;
    int* deg    = (int*)(t2 + (size_t)N_NODES * 128);
    int* off    = deg + N_NODES;
    int* cursor = off + N_NODES + 1;
    int* nbr    = cursor + N_NODES;

    // ---- CSR build (once per launch) ----
    hipMemsetAsync(deg, 0, N_NODES * sizeof(int), stream);
    hist_kernel<<<(N_EDGES + 255) / 256, 256, 0, stream>>>(dst, deg, N_EDGES);
    scan_kernel<<<1, 1024, 0, stream>>>(deg, off, cursor, N_NODES);
    fill_kernel<<<(N_EDGES + 255) / 256, 256, 0, stream>>>(src, dst, cursor,
                                                           nbr, N_EDGES);

    // ---- Layer 1 ----
    gather_kernel<64><<<(N_NODES * 16 + 255) / 256, 256, 0, stream>>>(
        x, off, nbr, t1, N_NODES);
    gin_mlp_kernel<64, 128, 128, 8><<<(N_NODES + 7) / 8, 128, 0, stream>>>(
        t1, W1a, b1a, W1b, b1b, h, N_NODES);

    // ---- Layer 2 ----
    gather_kernel<128><<<(N_NODES * 32 + 255) / 256, 256, 0, stream>>>(
        h, off, nbr, t2, N_NODES);
    gin_mlp_kernel<128, 128, 64, 8><<<(N_NODES + 7) / 8, 128, 0, stream>>>(
        t2, W2a, b2a, W2b, b2b, out, N_NODES);
}

// Round 3
// 386.565 us; speedup vs baseline: 5.7541x; 1.2327x over previous
//
#include <hip/hip_runtime.h>

#define N_NODES 50000
#define N_EDGES 800000

// ---------------------------------------------------------------------------
// CSR build (per launch; workspace is re-poisoned each call).
// deg -> 3-phase parallel exclusive scan -> off/cursor -> fill nbr with src.
// ---------------------------------------------------------------------------
__global__ void hist_kernel(const int* __restrict__ dst, int* __restrict__ deg,
                            int n) {
    int i = blockIdx.x * blockDim.x + threadIdx.x;
    if (i < n) atomicAdd(&deg[dst[i]], 1);
}

// Phase A: per-block sums of 1024-element chunks.
__global__ __launch_bounds__(1024) void scanA_kernel(
    const int* __restrict__ deg, int* __restrict__ bsum, int n) {
    __shared__ int s[1024];
    const int tid = threadIdx.x;
    int i = blockIdx.x * 1024 + tid;
    s[tid] = (i < n) ? deg[i] : 0;
    __syncthreads();
    for (int d = 512; d > 0; d >>= 1) {
        if (tid < d) s[tid] += s[tid + d];
        __syncthreads();
    }
    if (tid == 0) bsum[blockIdx.x] = s[0];
}

// Phase B: exclusive scan of block sums (nb <= 64), one wave.
__global__ __launch_bounds__(64) void scanB_kernel(int* __restrict__ bsum,
                                                   int nb) {
    const int tid = threadIdx.x;
    int v = (tid < nb) ? bsum[tid] : 0;
    for (int d = 1; d < 64; d <<= 1) {
        int t = __shfl_up(v, d, 64);
        if (tid >= d) v += t;
    }
    int excl = __shfl_up(v, 1, 64);
    if (tid == 0) excl = 0;
    if (tid < nb) bsum[tid] = excl;
}

// Phase C: in-block exclusive scan + block prefix -> off/cursor.
__global__ __launch_bounds__(1024) void scanC_kernel(
    const int* __restrict__ deg, const int* __restrict__ bpref,
    int* __restrict__ off, int* __restrict__ cursor, int n) {
    __shared__ int s[1024];
    const int tid = threadIdx.x;
    const int i = blockIdx.x * 1024 + tid;
    const int v = (i < n) ? deg[i] : 0;
    s[tid] = v;
    __syncthreads();
    for (int d = 1; d < 1024; d <<= 1) {
        int t = (tid >= d) ? s[tid - d] : 0;
        __syncthreads();
        s[tid] += t;
        __syncthreads();
    }
    const int excl = s[tid] - v + bpref[blockIdx.x];
    if (i < n) {
        off[i] = excl;
        cursor[i] = excl;
        if (i == n - 1) off[n] = excl + v;
    }
}

__global__ void fill_kernel(const int* __restrict__ src,
                            const int* __restrict__ dst,
                            int* __restrict__ cursor, int* __restrict__ nbr,
                            int n) {
    int i = blockIdx.x * blockDim.x + threadIdx.x;
    if (i < n) {
        int pos = atomicAdd(&cursor[dst[i]], 1);
        nbr[pos] = src[i];
    }
}

// ---------------------------------------------------------------------------
// Gather aggregation: t[i] = x[i] + sum_{j in N(i)} x[j].  D/4 lanes per node,
// float4 per lane; each neighbor row is a coalesced 256/512B burst from
// L2/LLC (x is 12.8/25.6 MB, cache-resident). No float atomics.
// ---------------------------------------------------------------------------
template <int D>
__global__ void gather_kernel(const float* __restrict__ x,
                              const int* __restrict__ off,
                              const int* __restrict__ nbr,
                              float* __restrict__ t, int n_nodes) {
    constexpr int C = D / 4;      // lanes per node
    constexpr int NPB = 256 / C;  // nodes per block
    const int tid = threadIdx.x;
    const int node = blockIdx.x * NPB + tid / C;
    const int c = tid % C;
    if (node >= n_nodes) return;
    const int lo = off[node];
    const int hi = off[node + 1];
    float4 acc = *reinterpret_cast<const float4*>(x + (size_t)node * D + c * 4);
    for (int j = lo; j < hi; ++j) {
        const int s = nbr[j];  // broadcast across the node's lane group
        const float4 v =
            *reinterpret_cast<const float4*>(x + (size_t)s * D + c * 4);
        acc.x += v.x; acc.y += v.y; acc.z += v.z; acc.w += v.w;
    }
    *reinterpret_cast<float4*>(t + (size_t)node * D + c * 4) = acc;
}

// ---------------------------------------------------------------------------
// Fused GIN MLP on pre-aggregated input t:
//   out = relu( relu(t @ Wa + ba) @ Wb + bb )
// Block = DH threads, ROWS rows per block. LDS reads are wave-uniform
// broadcasts; W reads coalesced across tid, amortized over ROWS FMAs.
// ---------------------------------------------------------------------------
template <int DIN, int DH, int DOUT, int ROWS>
__global__ __launch_bounds__(DH) void gin_mlp_kernel(
    const float* __restrict__ t, const float* __restrict__ Wa,
    const float* __restrict__ ba, const float* __restrict__ Wb,
    const float* __restrict__ bb, float* __restrict__ out, int n_rows) {
    __shared__ float t_lds[ROWS * DIN];
    __shared__ float hid_lds[ROWS * DH];

    const int row0 = blockIdx.x * ROWS;
    const int tid = threadIdx.x;

    constexpr int TOTAL = ROWS * DIN;
    for (int i = tid; i < TOTAL; i += DH) {
        int gr = row0 + i / DIN;
        t_lds[i] = (gr < n_rows) ? t[(size_t)gr * DIN + (i % DIN)] : 0.0f;
    }
    __syncthreads();

    {
        float acc[ROWS];
        const float bias = ba[tid];
#pragma unroll
        for (int r = 0; r < ROWS; ++r) acc[r] = bias;
        for (int k = 0; k < DIN; ++k) {
            float w = Wa[k * DH + tid];
#pragma unroll
            for (int r = 0; r < ROWS; ++r)
                acc[r] = fmaf(t_lds[r * DIN + k], w, acc[r]);
        }
#pragma unroll
        for (int r = 0; r < ROWS; ++r)
            hid_lds[r * DH + tid] = fmaxf(acc[r], 0.0f);
    }
    __syncthreads();

    if (tid < DOUT) {
        float acc[ROWS];
        const float bias = bb[tid];
#pragma unroll
        for (int r = 0; r < ROWS; ++r) acc[r] = bias;
        for (int k = 0; k < DH; ++k) {
            float w = Wb[k * DOUT + tid];
#pragma unroll
            for (int r = 0; r < ROWS; ++r)
                acc[r] = fmaf(hid_lds[r * DH + k], w, acc[r]);
        }
#pragma unroll
        for (int r = 0; r < ROWS; ++r) {
            int gr = row0 + r;
            if (gr < n_rows) out[(size_t)gr * DOUT + tid] = fmaxf(acc[r], 0.0f);
        }
    }
}

extern "C" void kernel_launch(void* const* d_in, const int* in_sizes, int n_in,
                              void* d_out, int out_size, void* d_ws,
                              size_t ws_size, hipStream_t stream) {
    const float* x   = (const float*)d_in[0];
    const int*   ei  = (const int*)d_in[1];  // [2, N_EDGES] int32
    const float* W1a = (const float*)d_in[2];
    const float* b1a = (const float*)d_in[3];
    const float* W1b = (const float*)d_in[4];
    const float* b1b = (const float*)d_in[5];
    const float* W2a = (const float*)d_in[6];
    const float* b2a = (const float*)d_in[7];
    const float* W2b = (const float*)d_in[8];
    const float* b2b = (const float*)d_in[9];
    float* out = (float*)d_out;

    const int* src = ei;
    const int* dst = ei + N_EDGES;

    // Workspace: t1[N,64] | h[N,128] | t2[N,128] |
    //            deg[N] off[N+1] cur[N] nbr[E] bsum[64]
    float* t1 = (float*)d_ws;
    float* h  = t1 + (size_t)N_NODES * 64;
    float* t2 = h + (size_t)N_NODES * 128;
    int* deg    = (int*)(t2 + (size_t)N_NODES * 128);
    int* off    = deg + N_NODES;
    int* cursor = off + N_NODES + 1;
    int* nbr    = cursor + N_NODES;
    int* bsum   = nbr + N_EDGES;

    constexpr int NB = (N_NODES + 1023) / 1024;  // 49 scan blocks

    // ---- CSR build (once per launch) ----
    hipMemsetAsync(deg, 0, N_NODES * sizeof(int), stream);
    hist_kernel<<<(N_EDGES + 255) / 256, 256, 0, stream>>>(dst, deg, N_EDGES);
    scanA_kernel<<<NB, 1024, 0, stream>>>(deg, bsum, N_NODES);
    scanB_kernel<<<1, 64, 0, stream>>>(bsum, NB);
    scanC_kernel<<<NB, 1024, 0, stream>>>(deg, bsum, off, cursor, N_NODES);
    fill_kernel<<<(N_EDGES + 255) / 256, 256, 0, stream>>>(src, dst, cursor,
                                                           nbr, N_EDGES);

    // ---- Layer 1 ----
    gather_kernel<64><<<(N_NODES * 16 + 255) / 256, 256, 0, stream>>>(
        x, off, nbr, t1, N_NODES);
    gin_mlp_kernel<64, 128, 128, 8><<<(N_NODES + 7) / 8, 128, 0, stream>>>(
        t1, W1a, b1a, W1b, b1b, h, N_NODES);

    // ---- Layer 2 ----
    gather_kernel<128><<<(N_NODES * 32 + 255) / 256, 256, 0, stream>>>(
        h, off, nbr, t2, N_NODES);
    gin_mlp_kernel<128, 128, 64, 8><<<(N_NODES + 7) / 8, 128, 0, stream>>>(
        t2, W2a, b2a, W2b, b2b, out, N_NODES);
}

// Round 4
// 302.514 us; speedup vs baseline: 7.3528x; 1.2778x over previous
//
#include <hip/hip_runtime.h>

#define N_NODES 50000
#define N_EDGES 800000

typedef __attribute__((ext_vector_type(8))) short short8;
typedef __attribute__((ext_vector_type(4))) float floatx4;

// float -> bf16 bits, round-to-nearest-even
static __device__ __forceinline__ unsigned short f2b(float f) {
    unsigned int u = __float_as_uint(f);
    unsigned int r = u + 0x7fffu + ((u >> 16) & 1u);
    return (unsigned short)(r >> 16);
}
// low/high bf16 of a packed uint -> float
static __device__ __forceinline__ float blo(unsigned int u) {
    return __uint_as_float(u << 16);
}
static __device__ __forceinline__ float bhi(unsigned int u) {
    return __uint_as_float(u & 0xffff0000u);
}

// ---------------------------------------------------------------------------
// CSR build: histogram -> 3-phase parallel exclusive scan -> fill.
// ---------------------------------------------------------------------------
__global__ void hist_kernel(const int* __restrict__ dst, int* __restrict__ deg,
                            int n) {
    int i = blockIdx.x * blockDim.x + threadIdx.x;
    if (i < n) atomicAdd(&deg[dst[i]], 1);
}

__global__ __launch_bounds__(1024) void scanA_kernel(
    const int* __restrict__ deg, int* __restrict__ bsum, int n) {
    __shared__ int s[1024];
    const int tid = threadIdx.x;
    int i = blockIdx.x * 1024 + tid;
    s[tid] = (i < n) ? deg[i] : 0;
    __syncthreads();
    for (int d = 512; d > 0; d >>= 1) {
        if (tid < d) s[tid] += s[tid + d];
        __syncthreads();
    }
    if (tid == 0) bsum[blockIdx.x] = s[0];
}

__global__ __launch_bounds__(64) void scanB_kernel(int* __restrict__ bsum,
                                                   int nb) {
    const int tid = threadIdx.x;
    int v = (tid < nb) ? bsum[tid] : 0;
    for (int d = 1; d < 64; d <<= 1) {
        int t = __shfl_up(v, d, 64);
        if (tid >= d) v += t;
    }
    int excl = __shfl_up(v, 1, 64);
    if (tid == 0) excl = 0;
    if (tid < nb) bsum[tid] = excl;
}

__global__ __launch_bounds__(1024) void scanC_kernel(
    const int* __restrict__ deg, const int* __restrict__ bpref,
    int* __restrict__ off, int* __restrict__ cursor, int n) {
    __shared__ int s[1024];
    const int tid = threadIdx.x;
    const int i = blockIdx.x * 1024 + tid;
    const int v = (i < n) ? deg[i] : 0;
    s[tid] = v;
    __syncthreads();
    for (int d = 1; d < 1024; d <<= 1) {
        int t = (tid >= d) ? s[tid - d] : 0;
        __syncthreads();
        s[tid] += t;
        __syncthreads();
    }
    const int excl = s[tid] - v + bpref[blockIdx.x];
    if (i < n) {
        off[i] = excl;
        cursor[i] = excl;
        if (i == n - 1) off[n] = excl + v;
    }
}

__global__ void fill_kernel(const int* __restrict__ src,
                            const int* __restrict__ dst,
                            int* __restrict__ cursor, int* __restrict__ nbr,
                            int n) {
    int i = blockIdx.x * blockDim.x + threadIdx.x;
    if (i < n) {
        int pos = atomicAdd(&cursor[dst[i]], 1);
        nbr[pos] = src[i];
    }
}

// ---------------------------------------------------------------------------
// Weight prep: transpose to [N][K] row-major and convert to bf16, so a
// B-fragment lane (col n = lane&15, k = quad*8+j) is one contiguous 16B load.
// ---------------------------------------------------------------------------
__global__ __launch_bounds__(256) void prep_weights_kernel(
    const float* __restrict__ W1a, const float* __restrict__ W1b,
    const float* __restrict__ W2a, const float* __restrict__ W2b,
    unsigned short* __restrict__ W1aT, unsigned short* __restrict__ W1bT,
    unsigned short* __restrict__ W2aT, unsigned short* __restrict__ W2bT) {
    int i = blockIdx.x * 256 + threadIdx.x;
    if (i < 8192) {                       // W1a [64][128] -> [128][64]
        int n = i >> 6, k = i & 63;
        W1aT[i] = f2b(W1a[k * 128 + n]);
    } else if (i < 24576) {               // W1b [128][128] -> [128][128]
        int j = i - 8192, n = j >> 7, k = j & 127;
        W1bT[j] = f2b(W1b[k * 128 + n]);
    } else if (i < 40960) {               // W2a [128][128] -> [128][128]
        int j = i - 24576, n = j >> 7, k = j & 127;
        W2aT[j] = f2b(W2a[k * 128 + n]);
    } else if (i < 49152) {               // W2b [128][64] -> [64][128]
        int j = i - 40960, n = j >> 7, k = j & 127;
        W2bT[j] = f2b(W2b[k * 64 + n]);
    }
}

// ---------------------------------------------------------------------------
// Gather layer 1: t1 = bf16(x + sum_nbr x), x fp32 [N][64].
// 16 lanes/node, one float4 (16B) per lane; fp32 accumulate, bf16 store.
// ---------------------------------------------------------------------------
__global__ __launch_bounds__(256) void gather1_kernel(
    const float* __restrict__ x, const int* __restrict__ off,
    const int* __restrict__ nbr, unsigned short* __restrict__ t1,
    int n_nodes) {
    const int tid = threadIdx.x;
    const int node = blockIdx.x * 16 + (tid >> 4);
    const int c = tid & 15;
    if (node >= n_nodes) return;
    const float4* x4 = (const float4*)x;
    float4 acc = x4[node * 16 + c];
    const int lo = off[node], hi = off[node + 1];
    for (int j = lo; j < hi; ++j) {
        const int s = nbr[j];
        const float4 v = x4[s * 16 + c];
        acc.x += v.x; acc.y += v.y; acc.z += v.z; acc.w += v.w;
    }
    uint2 o;
    o.x = (unsigned)f2b(acc.x) | ((unsigned)f2b(acc.y) << 16);
    o.y = (unsigned)f2b(acc.z) | ((unsigned)f2b(acc.w) << 16);
    ((uint2*)t1)[node * 16 + c] = o;
}

// ---------------------------------------------------------------------------
// Gather layer 2: t2 = bf16(h + sum_nbr h), h bf16 [N][128] (half traffic).
// 16 lanes/node, one uint4 = 8 bf16 per lane; fp32 accumulate.
// ---------------------------------------------------------------------------
__global__ __launch_bounds__(256) void gather2_kernel(
    const unsigned short* __restrict__ h, const int* __restrict__ off,
    const int* __restrict__ nbr, unsigned short* __restrict__ t2,
    int n_nodes) {
    const int tid = threadIdx.x;
    const int node = blockIdx.x * 16 + (tid >> 4);
    const int c = tid & 15;
    if (node >= n_nodes) return;
    const uint4* h4 = (const uint4*)h;
    uint4 a = h4[node * 16 + c];
    float f0 = blo(a.x), f1 = bhi(a.x), f2 = blo(a.y), f3 = bhi(a.y);
    float f4 = blo(a.z), f5 = bhi(a.z), f6 = blo(a.w), f7 = bhi(a.w);
    const int lo = off[node], hi = off[node + 1];
    for (int j = lo; j < hi; ++j) {
        const int s = nbr[j];
        const uint4 v = h4[s * 16 + c];
        f0 += blo(v.x); f1 += bhi(v.x); f2 += blo(v.y); f3 += bhi(v.y);
        f4 += blo(v.z); f5 += bhi(v.z); f6 += blo(v.w); f7 += bhi(v.w);
    }
    uint4 o;
    o.x = (unsigned)f2b(f0) | ((unsigned)f2b(f1) << 16);
    o.y = (unsigned)f2b(f2) | ((unsigned)f2b(f3) << 16);
    o.z = (unsigned)f2b(f4) | ((unsigned)f2b(f5) << 16);
    o.w = (unsigned)f2b(f6) | ((unsigned)f2b(f7) << 16);
    ((uint4*)t2)[node * 16 + c] = o;
}

// ---------------------------------------------------------------------------
// Fused 2-layer MLP via MFMA 16x16x32 bf16, fp32 accumulate.
//   out = relu( relu(T @ Wa + ba) @ Wb + bb )
// Block = 256 thr (4 waves), M_TILE = 64 rows; wave w owns rows [w*16,w*16+16).
// A fragments: lane (m=lane&15, k=quad*8+j) -> contiguous 16B ds_read_b128
// from row-major LDS (rows padded +16 bf16 to cut bank conflicts to 4-way).
// B fragments: lane (n=lane&15, k=quad*8+j) -> contiguous 16B global load
// from transposed [N][K] bf16 weights (L2/L1-resident, shared by all blocks).
// C/D layout: col=lane&15, row=quad*4+reg (verified m89/m91).
// Phase1 hidden tile -> LDS bf16; each wave only reads its own strip back,
// so no barrier between phases (same-wave ds ordering via lgkmcnt).
// ---------------------------------------------------------------------------
template <int DIN, int DH, int DOUT, bool OUT_BF16>
__global__ __launch_bounds__(256) void mlp_mfma_kernel(
    const unsigned short* __restrict__ t, const unsigned short* __restrict__ WaT,
    const float* __restrict__ ba, const unsigned short* __restrict__ WbT,
    const float* __restrict__ bb, void* __restrict__ outp, int n_rows) {
    constexpr int SA = DIN + 16;   // padded LDS row (elements)
    constexpr int SH = DH + 16;
    __shared__ unsigned short tA[64 * SA];
    __shared__ unsigned short hidA[64 * SH];

    const int tid = threadIdx.x;
    const int row0 = blockIdx.x * 64;

    // Stage 64 rows of T (bf16) into padded LDS; 16B per thread per iter.
    constexpr int CHUNKS = 64 * DIN / 8;
    const uint4* tg = (const uint4*)t;
    for (int i = tid; i < CHUNKS; i += 256) {
        const int row = i / (DIN / 8);
        const int cb = i % (DIN / 8);
        uint4 v = {0u, 0u, 0u, 0u};
        const int gr = row0 + row;
        if (gr < n_rows) v = tg[(size_t)gr * (DIN / 8) + cb];
        *(uint4*)&tA[row * SA + cb * 8] = v;
    }
    __syncthreads();

    const int lane = tid & 63;
    const int wv = tid >> 6;
    const int quad = lane >> 4;
    const int l16 = lane & 15;
    const int m0 = wv * 16;

    // ---- Phase 1: hid = relu(T @ Wa + ba) ----
    short8 a1[DIN / 32];
#pragma unroll
    for (int kk = 0; kk < DIN / 32; ++kk)
        a1[kk] = *(const short8*)&tA[(m0 + l16) * SA + kk * 32 + quad * 8];
#pragma unroll
    for (int nt = 0; nt < DH / 16; ++nt) {
        floatx4 acc = {0.f, 0.f, 0.f, 0.f};
#pragma unroll
        for (int kk = 0; kk < DIN / 32; ++kk) {
            short8 b =
                *(const short8*)&WaT[(nt * 16 + l16) * DIN + kk * 32 + quad * 8];
            acc = __builtin_amdgcn_mfma_f32_16x16x32_bf16(a1[kk], b, acc, 0, 0, 0);
        }
        const float bias = ba[nt * 16 + l16];
#pragma unroll
        for (int r = 0; r < 4; ++r) {
            const float v = fmaxf(acc[r] + bias, 0.f);
            hidA[(m0 + quad * 4 + r) * SH + nt * 16 + l16] = f2b(v);
        }
    }

    // ---- Phase 2: out = relu(hid @ Wb + bb) ----  (same-wave strip only)
    short8 a2[DH / 32];
#pragma unroll
    for (int kk = 0; kk < DH / 32; ++kk)
        a2[kk] = *(const short8*)&hidA[(m0 + l16) * SH + kk * 32 + quad * 8];
#pragma unroll
    for (int nt = 0; nt < DOUT / 16; ++nt) {
        floatx4 acc = {0.f, 0.f, 0.f, 0.f};
#pragma unroll
        for (int kk = 0; kk < DH / 32; ++kk) {
            short8 b =
                *(const short8*)&WbT[(nt * 16 + l16) * DH + kk * 32 + quad * 8];
            acc = __builtin_amdgcn_mfma_f32_16x16x32_bf16(a2[kk], b, acc, 0, 0, 0);
        }
        const float bias = bb[nt * 16 + l16];
#pragma unroll
        for (int r = 0; r < 4; ++r) {
            const float v = fmaxf(acc[r] + bias, 0.f);
            const int grow = row0 + m0 + quad * 4 + r;
            if (grow < n_rows) {
                if (OUT_BF16)
                    ((unsigned short*)outp)[(size_t)grow * DOUT + nt * 16 + l16] =
                        f2b(v);
                else
                    ((float*)outp)[(size_t)grow * DOUT + nt * 16 + l16] = v;
            }
        }
    }
}

extern "C" void kernel_launch(void* const* d_in, const int* in_sizes, int n_in,
                              void* d_out, int out_size, void* d_ws,
                              size_t ws_size, hipStream_t stream) {
    const float* x   = (const float*)d_in[0];
    const int*   ei  = (const int*)d_in[1];  // [2, N_EDGES] int32
    const float* W1a = (const float*)d_in[2];
    const float* b1a = (const float*)d_in[3];
    const float* W1b = (const float*)d_in[4];
    const float* b1b = (const float*)d_in[5];
    const float* W2a = (const float*)d_in[6];
    const float* b2a = (const float*)d_in[7];
    const float* W2b = (const float*)d_in[8];
    const float* b2b = (const float*)d_in[9];
    float* out = (float*)d_out;

    const int* src = ei;
    const int* dst = ei + N_EDGES;

    // Workspace: bf16 t1[N,64] | bf16 h[N,128] | bf16 t2[N,128] |
    //            bf16 W1aT/W1bT/W2aT/W2bT | int deg/off/cursor/nbr/bsum
    unsigned short* t1 = (unsigned short*)d_ws;
    unsigned short* h  = t1 + (size_t)N_NODES * 64;
    unsigned short* t2 = h + (size_t)N_NODES * 128;
    unsigned short* W1aT = t2 + (size_t)N_NODES * 128;
    unsigned short* W1bT = W1aT + 8192;
    unsigned short* W2aT = W1bT + 16384;
    unsigned short* W2bT = W2aT + 16384;
    int* deg    = (int*)(W2bT + 8192);
    int* off    = deg + N_NODES;
    int* cursor = off + N_NODES + 1;
    int* nbr    = cursor + N_NODES;
    int* bsum   = nbr + N_EDGES;

    constexpr int NB = (N_NODES + 1023) / 1024;  // 49 scan blocks

    // ---- CSR build ----
    hipMemsetAsync(deg, 0, N_NODES * sizeof(int), stream);
    hist_kernel<<<(N_EDGES + 255) / 256, 256, 0, stream>>>(dst, deg, N_EDGES);
    scanA_kernel<<<NB, 1024, 0, stream>>>(deg, bsum, N_NODES);
    scanB_kernel<<<1, 64, 0, stream>>>(bsum, NB);
    scanC_kernel<<<NB, 1024, 0, stream>>>(deg, bsum, off, cursor, N_NODES);
    fill_kernel<<<(N_EDGES + 255) / 256, 256, 0, stream>>>(src, dst, cursor,
                                                           nbr, N_EDGES);
    prep_weights_kernel<<<192, 256, 0, stream>>>(W1a, W1b, W2a, W2b, W1aT,
                                                 W1bT, W2aT, W2bT);

    // ---- Layer 1 ----
    gather1_kernel<<<N_NODES / 16, 256, 0, stream>>>(x, off, nbr, t1, N_NODES);
    mlp_mfma_kernel<64, 128, 128, true>
        <<<(N_NODES + 63) / 64, 256, 0, stream>>>(t1, W1aT, b1a, W1bT, b1b, h,
                                                  N_NODES);

    // ---- Layer 2 ----
    gather2_kernel<<<N_NODES / 16, 256, 0, stream>>>(h, off, nbr, t2, N_NODES);
    mlp_mfma_kernel<128, 128, 64, false>
        <<<(N_NODES + 63) / 64, 256, 0, stream>>>(t2, W2aT, b2a, W2bT, b2b, out,
                                                  N_NODES);
}